// Round 12
// baseline (5544.261 us; speedup 1.0000x reference)
//
#include <hip/hip_runtime.h>
#include <hip/hip_bf16.h>

// LSTM: B=64, S=512, D=512, H=1024, L=2, O=256
// Persistent kernel, deep-pipelined DMA staging, 128 WGs x 512 threads:
//   - 64 WGs/layer, 16 h-columns each; 8 waves = 4 K-slices x 2 column-groups.
//   - A-panel staged via global_load_lds into an 8-slot LDS ring, lookahead 7,
//     statically counted vmcnt (compile-time FIFO sim).
//   - x staging DMA is NON-TEMPORAL (CPol NT) so it can't evict the L2-resident
//     weight slice; h staging bypasses L2 entirely (sc0 sc1, IF-coherent).
//   - weights streamed from L2 into a depth-8 VGPR ring (covers IF-latency misses).
//   - fence-free relaxed-atomic grid barrier; c-state in registers.

namespace {
constexpr int Bn = 64, Sn = 512, Dn = 512, Hn = 1024, On = 256;
constexpr int BH = Bn * Hn;        // 65536
constexpr int SLAB = BH * 2;       // 131072 bytes per h slab (bf16)
}

typedef unsigned short u16;
typedef unsigned int u32;
typedef float f32x4 __attribute__((ext_vector_type(4)));
typedef short s16x8 __attribute__((ext_vector_type(8)));
typedef unsigned int u32x4 __attribute__((ext_vector_type(4)));

__device__ __forceinline__ u16 f2bf(float f) {
    unsigned int u = __float_as_uint(f);
    unsigned int r = (u + 0x7fffu + ((u >> 16) & 1u)) >> 16;
    return (u16)r;
}
__device__ __forceinline__ float bf2f(u16 b) {
    return __uint_as_float(((unsigned int)b) << 16);
}
__device__ __forceinline__ float sigmf(float x) { return 1.0f / (1.0f + __expf(-x)); }

// ---- coherent primitives (no cache-maintenance ops) ----
__device__ __forceinline__ void stg_coh128(u16* p, u32x4 v) {
    asm volatile("global_store_dwordx4 %0, %1, off sc0 sc1" :: "v"(p), "v"(v) : "memory");
}
__device__ __forceinline__ u32 ldg_coh_u32(const u32* p) {
    u32 r;
    asm volatile("global_load_dword %0, %1, off sc0 sc1" : "=&v"(r) : "v"(p) : "memory");
    return r;
}
// plain 16B load as volatile asm (deterministic single VMEM instruction)
__device__ __forceinline__ s16x8 ldg_pin(const u16* p) {
    s16x8 r;
    asm volatile("global_load_dwordx4 %0, %1, off" : "=&v"(r) : "v"(p) : "memory");
    return r;
}
__device__ __forceinline__ void waitvm0() {
    asm volatile("s_waitcnt vmcnt(0)" ::: "memory");
    __builtin_amdgcn_sched_barrier(0);
}

// ---- DMA global->LDS (16B/lane). dst wave-uniform; lane*16 implicit.
// aux CPol bits (gfx950): SC0=1, NT=2, SC1=16.
__device__ __forceinline__ void dmaAnt(const void* src, void* dst) {
    // non-temporal: stream through L2 without displacing resident (weight) lines
    __builtin_amdgcn_global_load_lds((const __attribute__((address_space(1))) void*)src,
                                     (__attribute__((address_space(3))) void*)dst, 16, 0, 2);
}
__device__ __forceinline__ void dmaAcoh(const void* src, void* dst) {
    // SC0|SC1 = 17: IF-coherent read (bypass stale L2)
    __builtin_amdgcn_global_load_lds((const __attribute__((address_space(1))) void*)src,
                                     (__attribute__((address_space(3))) void*)dst, 16, 0, 17);
}

template <int I> struct IC { static constexpr int v = I; };
template <int N, int I = 0, typename F>
__device__ __forceinline__ void sfor(F&& f) {
    if constexpr (I < N) { f(IC<I>{}); sfor<N, I + 1, F>(static_cast<F&&>(f)); }
}

// ---- static vmcnt schedule: FIFO sim. Per chunk: A=2 DMA instrs, W=2 loads.
// [prologue A0..LA-1, Wt0..DW-1; iter i: wait(i) | issue A(i+LA) | consume | issue Wt(i+DW)]
constexpr int WN(int c, int NC, int LA, int DW) {
    int posA[40] = {}, posW[40] = {};
    int pos = 0;
    const int nA = NC < LA ? NC : LA;
    for (int k = 0; k < nA; ++k) { pos += 2; posA[k] = pos; }
    const int nW = NC < DW ? NC : DW;
    for (int k = 0; k < nW; ++k) { pos += 2; posW[k] = pos; }
    for (int i = 0; i < NC; ++i) {
        if (i == c) {
            const int la = posA[c], lw = posW[c];
            const int last = la > lw ? la : lw;
            return pos - last;
        }
        if (i + LA < NC) { pos += 2; posA[i + LA] = pos; }
        if (i + DW < NC) { pos += 2; posW[i + DW] = pos; }
    }
    return 0;
}

template <int N> __device__ __forceinline__ void waitvmN() {
    static_assert(N >= 0 && N <= 32 && (N % 2 == 0), "unexpected vmcnt");
    if constexpr (N == 0)  asm volatile("s_waitcnt vmcnt(0)" ::: "memory");
    else if constexpr (N == 2)  asm volatile("s_waitcnt vmcnt(2)" ::: "memory");
    else if constexpr (N == 4)  asm volatile("s_waitcnt vmcnt(4)" ::: "memory");
    else if constexpr (N == 6)  asm volatile("s_waitcnt vmcnt(6)" ::: "memory");
    else if constexpr (N == 8)  asm volatile("s_waitcnt vmcnt(8)" ::: "memory");
    else if constexpr (N == 10) asm volatile("s_waitcnt vmcnt(10)" ::: "memory");
    else if constexpr (N == 12) asm volatile("s_waitcnt vmcnt(12)" ::: "memory");
    else if constexpr (N == 14) asm volatile("s_waitcnt vmcnt(14)" ::: "memory");
    else if constexpr (N == 16) asm volatile("s_waitcnt vmcnt(16)" ::: "memory");
    else if constexpr (N == 18) asm volatile("s_waitcnt vmcnt(18)" ::: "memory");
    else if constexpr (N == 20) asm volatile("s_waitcnt vmcnt(20)" ::: "memory");
    else if constexpr (N == 22) asm volatile("s_waitcnt vmcnt(22)" ::: "memory");
    else if constexpr (N == 24) asm volatile("s_waitcnt vmcnt(24)" ::: "memory");
    else if constexpr (N == 26) asm volatile("s_waitcnt vmcnt(26)" ::: "memory");
    else if constexpr (N == 28) asm volatile("s_waitcnt vmcnt(28)" ::: "memory");
    else if constexpr (N == 30) asm volatile("s_waitcnt vmcnt(30)" ::: "memory");
    else if constexpr (N == 32) asm volatile("s_waitcnt vmcnt(32)" ::: "memory");
    __builtin_amdgcn_sched_barrier(0);
}

// Pf bank-swizzled index: row-major [256][64] f32 with XOR on the m index.
__device__ __forceinline__ int PFI(int row, int m) {
    return row * 64 + (m ^ ((row & 7) << 2));
}

// ---------------- prep (unchanged) ----------------
__global__ void prep_kernel(const float* __restrict__ Wx0, const float* __restrict__ Wh0,
                            const float* __restrict__ bx0, const float* __restrict__ bh0,
                            const float* __restrict__ Wx1, const float* __restrict__ Wh1,
                            const float* __restrict__ bx1, const float* __restrict__ bh1,
                            const float* __restrict__ h0in, const float* __restrict__ x,
                            u16* __restrict__ Wpk0, u16* __restrict__ Wpk1,
                            u16* __restrict__ xpk, float* __restrict__ bcomb,
                            u16* __restrict__ h0buf, u16* __restrict__ h1buf,
                            u32* __restrict__ cnt) {
    const long long idx = (long long)blockIdx.x * 256 + threadIdx.x;
    const long long stride = (long long)gridDim.x * 256;
    if (idx < 8) cnt[idx * 16] = 0u;   // 8 counters, 64B apart

    for (long long i = idx; i < 128LL * 4 * 24 * 512; i += stride) {
        const int j = (int)(i & 7);
        const int lane = (int)((i >> 3) & 63);
        const int f = (int)(i >> 9);
        const int nt = f & 1;
        const int q = f >> 1;
        const int c = q % 12, r = q / 12;
        const int wv = r & 3, wg = r >> 2;
        const int pr = lane & 15, lh = lane >> 4;
        const int row = (nt * 2 + (pr >> 3)) * 1024 + wg * 8 + (pr & 7);
        const int k = (c * 4 + wv) * 32 + lh * 8 + j;
        const float v = (k < 512) ? Wx0[(size_t)row * 512 + k] : Wh0[(size_t)row * 1024 + (k - 512)];
        Wpk0[i] = f2bf(v);
    }
    for (long long i = idx; i < 128LL * 4 * 32 * 512; i += stride) {
        const int j = (int)(i & 7);
        const int lane = (int)((i >> 3) & 63);
        const int f = (int)(i >> 9);
        const int nt = f & 1;
        const int q = f >> 1;
        const int c = q & 15, r = q >> 4;
        const int wv = r & 3, wg = r >> 2;
        const int pr = lane & 15, lh = lane >> 4;
        const int row = (nt * 2 + (pr >> 3)) * 1024 + wg * 8 + (pr & 7);
        const int k = (c * 4 + wv) * 32 + lh * 8 + j;
        const float v = (k < 1024) ? Wx1[(size_t)row * 1024 + k] : Wh1[(size_t)row * 1024 + (k - 1024)];
        Wpk1[i] = f2bf(v);
    }
    // x -> bf16 [t][b][d]
    for (long long bi = idx; bi < 512LL * 64 * 64; bi += stride) {
        const int db = (int)(bi & 63);
        const int r = (int)((bi >> 6) & 63);
        const int t = (int)(bi >> 12);
        const float* sp = x + ((size_t)r * Sn + t) * Dn + db * 8;
        const float4 a = *(const float4*)sp;
        const float4 b = *(const float4*)(sp + 4);
        s16x8 v;
        v[0] = (short)f2bf(a.x); v[1] = (short)f2bf(a.y); v[2] = (short)f2bf(a.z); v[3] = (short)f2bf(a.w);
        v[4] = (short)f2bf(b.x); v[5] = (short)f2bf(b.y); v[6] = (short)f2bf(b.z); v[7] = (short)f2bf(b.w);
        *(s16x8*)&xpk[bi * 8] = v;
    }
    for (long long i = idx; i < 4096; i += stride) {
        bcomb[i] = bx0[i] + bh0[i];
        bcomb[4096 + i] = bx1[i] + bh1[i];
    }
    // initial h states: parity-1 slabs, PRE-SWIZZLED block layout
    for (long long bi = idx; bi < 8192; bi += stride) {
        const int ck = (int)(bi >> 10), w = (int)(bi & 1023);
        const int r = w >> 4, b = w & 15;
        const int cbl = b ^ (r & 7);
        const int k = ck * 128 + cbl * 8;
        s16x8 v0, v1;
#pragma unroll
        for (int j = 0; j < 8; ++j) {
            v0[j] = (short)f2bf(h0in[(size_t)r * Hn + k + j]);
            v1[j] = (short)f2bf(h0in[(size_t)BH + r * Hn + k + j]);
        }
        *(s16x8*)&h0buf[65536 + bi * 8] = v0;
        *(s16x8*)&h1buf[65536 + bi * 8] = v1;
    }
}

// ---------------- fence-free bounded grid barrier (128 arrivals/phase) ----------------
__device__ __forceinline__ void gbar(u32* cbase, int slot, u32 tgt, int& dead) {
    waitvm0();
    __syncthreads();
    if (threadIdx.x == 0 && !dead) {
        atomicAdd(cbase + slot * 16, 1u);
        int guard = 0;
        for (;;) {
            u32 t0 = ldg_coh_u32(cbase + 0 * 16), t1 = ldg_coh_u32(cbase + 1 * 16);
            u32 t2 = ldg_coh_u32(cbase + 2 * 16), t3 = ldg_coh_u32(cbase + 3 * 16);
            u32 t4 = ldg_coh_u32(cbase + 4 * 16), t5 = ldg_coh_u32(cbase + 5 * 16);
            u32 t6 = ldg_coh_u32(cbase + 6 * 16), t7 = ldg_coh_u32(cbase + 7 * 16);
            waitvm0();
            if (t0 + t1 + t2 + t3 + t4 + t5 + t6 + t7 >= tgt) break;
            __builtin_amdgcn_s_sleep(1);
            if (++guard > (1 << 13)) { dead = 1; break; }
        }
    }
    __syncthreads();
}

// ---------------- per-layer persistent loop ----------------
// NC chunks (L0:12, L1:16); XC = chunks from first source (L0: xpk 4; L1: h0 8)
// 8 waves: wave wid -> K-slice ks=wid&3, column-group cg=wid>>2; 16 cols per WG.
template <int NC, int XC, int LAYER>
__device__ __forceinline__ void run_layer(const u16* __restrict__ xpk,
                                          const u16* __restrict__ Wpk,
                                          const float* __restrict__ bias,
                                          const float* __restrict__ c0in,
                                          u16* h0buf, u16* h1buf, u16* h1fin,
                                          u32* cnt, int wg, int slot, char* smem) {
    constexpr int LA = 7, DW = 8;          // A lookahead (ring 8), weight reg-ring depth
    const int tid = threadIdx.x;
    const int wid = tid >> 6, lane = tid & 63;
    const int ks = wid & 3, cg = wid >> 2;
    const int ln15 = lane & 15, lhi = lane >> 4;
    const int vg = wg * 2 + cg;            // virtual 8-col group index in [0,128)
    const int col0 = wg * 16;
    const int m_u = tid & 63, cp_u = tid >> 6;   // cell update: (m, col pair cp_u in [0,8))
    int dead = 0;
    float* Pf = (float*)smem;              // epilogue overlay (ring slots 0-3, 64 KB)
    u32* hstg = (u32*)(smem + 65536);      // epilogue overlay (slot 4 head, 2 KB)

    const u16* wbase = Wpk + ((size_t)(vg * 4 + ks) * (2 * NC)) * 512 + lane * 8;
    s16x8 wfr[DW][2];

    // xpk per-issue lane offsets (L0): issue i covers row r = wid*8 + i*4 + lhi, block ln15
    int xoff[2];
    if constexpr (LAYER == 0) {
#pragma unroll
        for (int i = 0; i < 2; ++i) {
            const int r = wid * 8 + i * 4 + lhi;
            const int cbl = ln15 ^ (r & 7);
            xoff[i] = r * 1024 + cbl * 16;   // + c*256 per chunk
        }
    }

    float bR[4][2];
#pragma unroll
    for (int g = 0; g < 4; ++g) {
        bR[g][0] = bias[g * 1024 + col0 + cp_u * 2 + 0];
        bR[g][1] = bias[g * 1024 + col0 + cp_u * 2 + 1];
    }
    float cr0 = c0in[(size_t)m_u * 1024 + col0 + cp_u * 2 + 0];
    float cr1 = c0in[(size_t)m_u * 1024 + col0 + cp_u * 2 + 1];

    for (int ph = 0; ph <= Sn; ++ph) {
        const bool active = (LAYER == 0) ? (ph < Sn) : (ph >= 1);
        if (active) {
            const int t = (LAYER == 0) ? ph : ph - 1;
            const char* hA = (const char*)h0buf + (size_t)((ph + 1) & 1) * SLAB;
            const char* hB = (const char*)h1buf + (size_t)(ph & 1) * SLAB;
            u16* hw = (LAYER == 0) ? (u16*)((char*)h0buf + (size_t)(ph & 1) * SLAB)
                                   : (u16*)((char*)h1buf + (size_t)((ph + 1) & 1) * SLAB);
            const char* xsl = (const char*)xpk + (size_t)t * 65536;
            const int wib = wid * 2048 + lane * 16;   // per-lane linear offset in a chunk

            auto issueA = [&](auto cc) {
                constexpr int c = cc.v;
                char* dst0 = smem + ((c & 7) << 14) + wid * 2048;
#pragma unroll
                for (int i = 0; i < 2; ++i) {
                    char* dst = dst0 + i * 1024;       // wave-uniform; +lane*16 implicit
                    if constexpr (LAYER == 0 && c < XC) {
                        dmaAnt(xsl + xoff[i] + c * 256, dst);           // NT: don't evict weights
                    } else if constexpr (LAYER == 0) {
                        dmaAcoh(hA + ((c - XC) << 14) + wib + i * 1024, dst);
                    } else if constexpr (c < XC) {
                        dmaAcoh(hA + (c << 14) + wib + i * 1024, dst);
                    } else {
                        dmaAcoh(hB + ((c - XC) << 14) + wib + i * 1024, dst);
                    }
                }
            };
            auto issueWt = [&](auto cc) {
                constexpr int c = cc.v;
                const u16* wp = wbase + (size_t)(2 * c) * 512;
                wfr[c % DW][0] = ldg_pin(wp);
                wfr[c % DW][1] = ldg_pin(wp + 512);
            };

            // prologue
            sfor<LA>([&](auto k) { issueA(k); });
            sfor<DW>([&](auto k) { issueWt(k); });

            f32x4 acc[4][2];
#pragma unroll
            for (int mi = 0; mi < 4; ++mi) {
                acc[mi][0] = f32x4{0.f, 0.f, 0.f, 0.f};
                acc[mi][1] = f32x4{0.f, 0.f, 0.f, 0.f};
            }

            sfor<NC>([&](auto cc) {
                constexpr int c = cc.v;
                waitvmN<WN(c, NC, LA, DW)>();          // own chunk-c DMA + Wt(c) done
                __builtin_amdgcn_s_barrier();          // all waves' chunk-c DMA landed
                __builtin_amdgcn_sched_barrier(0);
                if constexpr (c + LA < NC) issueA(IC<c + LA>{});
                const int ab = (c & 7) << 14;
#pragma unroll
                for (int mi = 0; mi < 4; ++mi) {
                    const int arow = mi * 16 + ln15;
                    const s16x8 af =
                        *(const s16x8*)&smem[ab + arow * 256 + (((ks * 4 + lhi) ^ (arow & 7)) << 4)];
                    acc[mi][0] = __builtin_amdgcn_mfma_f32_16x16x32_bf16(af, wfr[c % DW][0], acc[mi][0], 0, 0, 0);
                    acc[mi][1] = __builtin_amdgcn_mfma_f32_16x16x32_bf16(af, wfr[c % DW][1], acc[mi][1], 0, 0, 0);
                }
                // rewrite weight ring slot AFTER its consuming MFMAs (in-order issue -> safe)
                if constexpr (c + DW < NC) issueWt(IC<c + DW>{});
            });

            // ---- epilogue: cross-wave reduction (Pf overlays ring slots 0-3 -> sync first)
            __syncthreads();
#pragma unroll
            for (int mi = 0; mi < 4; ++mi)
#pragma unroll
                for (int nt = 0; nt < 2; ++nt)
#pragma unroll
                    for (int r = 0; r < 4; ++r) {
                        const int row = cg * 128 + ks * 32 + (nt * 2 + (ln15 >> 3)) * 8 + (ln15 & 7);
                        const int m = mi * 16 + lhi * 4 + r;
                        Pf[PFI(row, m)] = acc[mi][nt][r];
                    }
            __syncthreads();

            // ---- fused cell update: thread owns (m_u, cols col0+2cp_u .. +1)
            float sg[4][2];
#pragma unroll
            for (int g = 0; g < 4; ++g) { sg[g][0] = bR[g][0]; sg[g][1] = bR[g][1]; }
#pragma unroll
            for (int j = 0; j < 2; ++j) {
                const int ci = cp_u * 2 + j;
                const int cgj = ci >> 3, colw = ci & 7;
#pragma unroll
                for (int k2 = 0; k2 < 4; ++k2)
#pragma unroll
                    for (int g = 0; g < 4; ++g)
                        sg[g][j] += Pf[PFI(cgj * 128 + k2 * 32 + g * 8 + colw, m_u)];
            }
            const float i0 = sigmf(sg[0][0]), f0 = sigmf(sg[1][0]), g0 = tanhf(sg[2][0]), o0 = sigmf(sg[3][0]);
            const float i1 = sigmf(sg[0][1]), f1 = sigmf(sg[1][1]), g1 = tanhf(sg[2][1]), o1 = sigmf(sg[3][1]);
            cr0 = f0 * cr0 + i0 * g0;
            cr1 = f1 * cr1 + i1 * g1;
            const u16 hb0 = f2bf(o0 * tanhf(cr0));
            const u16 hb1 = f2bf(o1 * tanhf(cr1));
            hstg[m_u * 8 + cp_u] = (u32)hb0 | ((u32)hb1 << 16);
            __syncthreads();
            if (tid < 128) {   // one coherent 16B store per (row, 8-col half)
                const int r = tid >> 1, half = tid & 1;
                u32x4 hv;
                hv[0] = hstg[r * 8 + half * 4 + 0]; hv[1] = hstg[r * 8 + half * 4 + 1];
                hv[2] = hstg[r * 8 + half * 4 + 2]; hv[3] = hstg[r * 8 + half * 4 + 3];
                if (LAYER == 1 && ph == Sn) {
                    stg_coh128(&h1fin[(size_t)r * Hn + col0 + half * 8], hv);  // plain for FC
                } else {
                    const int cb = wg * 2 + half;          // block index in [0,128)
                    const int ck = cb >> 4, bl = cb & 15;
                    stg_coh128(hw + ck * 8192 + (r * 16 + (bl ^ (r & 7))) * 8, hv);
                }
            }
        }
        if (ph < Sn) gbar(cnt, slot, (u32)(ph + 1) * 128u, dead);
    }
    waitvm0();
}

__global__ __attribute__((amdgpu_flat_work_group_size(512, 512)))
void lstm_persist(const u16* __restrict__ xpk,
                  const u16* __restrict__ Wpk0,
                  const u16* __restrict__ Wpk1,
                  const float* __restrict__ bias,
                  const float* __restrict__ c0in,
                  u16* h0buf, u16* h1buf, u16* h1fin, u32* cnt) {
    __shared__ __align__(16) char smem[131072];   // 8-slot A ring; 1 WG/CU
    const int slot = blockIdx.x & 7;
    if (blockIdx.x < 64)
        run_layer<12, 4, 0>(xpk, Wpk0, bias, c0in, h0buf, h1buf, h1fin, cnt, blockIdx.x, slot, smem);
    else
        run_layer<16, 8, 1>(xpk, Wpk1, bias + 4096, c0in + BH, h0buf, h1buf, h1fin, cnt,
                            blockIdx.x - 64, slot, smem);
}

// ---------------- final FC + sigmoid ----------------
__global__ __launch_bounds__(256) void fc_out(const u16* __restrict__ h1,
                                              const float* __restrict__ fcW,
                                              const float* __restrict__ fcb,
                                              float* __restrict__ out) {
    const int b = blockIdx.x;  // 64
    __shared__ float hs[Hn];
    for (int k = threadIdx.x; k < Hn; k += 256) hs[k] = bf2f(h1[(size_t)b * Hn + k]);
    __syncthreads();
    const int o = threadIdx.x;  // 256
    float acc = fcb[o];
    const float4* wr = (const float4*)(fcW + (size_t)o * Hn);
    const float4* hv = (const float4*)hs;
#pragma unroll 8
    for (int k4 = 0; k4 < Hn / 4; ++k4) {
        const float4 w = wr[k4];
        const float4 h = hv[k4];
        acc += w.x * h.x + w.y * h.y + w.z * h.z + w.w * h.w;
    }
    out[(size_t)b * On + o] = sigmf(acc);
}

extern "C" void kernel_launch(void* const* d_in, const int* in_sizes, int n_in,
                              void* d_out, int out_size, void* d_ws, size_t ws_size,
                              hipStream_t stream) {
    (void)in_sizes; (void)n_in; (void)out_size; (void)ws_size;
    const float* x   = (const float*)d_in[0];
    const float* h0i = (const float*)d_in[1];
    const float* c0i = (const float*)d_in[2];
    const float* Wx0 = (const float*)d_in[3];
    const float* Wh0 = (const float*)d_in[4];
    const float* bx0 = (const float*)d_in[5];
    const float* bh0 = (const float*)d_in[6];
    const float* Wx1 = (const float*)d_in[7];
    const float* Wh1 = (const float*)d_in[8];
    const float* bx1 = (const float*)d_in[9];
    const float* bh1 = (const float*)d_in[10];
    const float* fcW = (const float*)d_in[11];
    const float* fcb = (const float*)d_in[12];
    float* out = (float*)d_out;

    char* ws = (char*)d_ws;
    u16* Wpk0   = (u16*)(ws + 0);            // 12,582,912 B
    u16* Wpk1   = (u16*)(ws + 12582912);     // 16,777,216 B
    u16* xpk    = (u16*)(ws + 29360128);     // 33,554,432 B  [t][b][d] bf16
    float* bias = (float*)(ws + 62914560);   // 32,768 B
    u16* h0buf  = (u16*)(ws + 62947328);     // 262,144 B (2 swizzled slabs)
    u16* h1buf  = (u16*)(ws + 63209472);     // 262,144 B
    u16* h1fin  = (u16*)(ws + 63471616);     // 131,072 B (plain, for FC)
    u32* cnt    = (u32*)(ws + 63602688);     // 512 B

    prep_kernel<<<2048, 256, 0, stream>>>(Wx0, Wh0, bx0, bh0, Wx1, Wh1, bx1, bh1,
                                          h0i, x, Wpk0, Wpk1, xpk, bias, h0buf, h1buf, cnt);

    lstm_persist<<<128, 512, 0, stream>>>(xpk, Wpk0, Wpk1, bias, c0i, h0buf, h1buf, h1fin, cnt);

    fc_out<<<64, 256, 0, stream>>>(h1fin, fcW, fcb, out);
}

// Round 14
// 5112.383 us; speedup vs baseline: 1.0845x; 1.0845x over previous
//
#include <hip/hip_runtime.h>
#include <hip/hip_bf16.h>

// LSTM: B=64, S=512, D=512, H=1024, L=2, O=256
// Persistent kernel, 128 WGs x 1024 threads (16 waves):
//   - wave = (cg:2)x(nt:2)x(ks:4) -> per-wave weights = NC frags (48-64 VGPR),
//     loaded ONCE into registers before the phase loop. Zero weight traffic/phase.
//   - A-panel staged via global_load_lds into an 8-slot LDS ring, lookahead 7;
//     vmcnt FIFO contains ONLY A-DMA -> clean counted waits per chunk.
//   - h slabs PRE-SWIZZLED so linear DMA writes produce the MFMA LDS layout.
//   - h coherence via sc0 sc1 (IF); fence-free relaxed-atomic grid barrier
//     (hardened: guard 2^12, dead-latch skips all later waits).

namespace {
constexpr int Bn = 64, Sn = 512, Dn = 512, Hn = 1024, On = 256;
constexpr int BH = Bn * Hn;        // 65536
constexpr int SLAB = BH * 2;       // 131072 bytes per h slab (bf16)
}

typedef unsigned short u16;
typedef unsigned int u32;
typedef float f32x4 __attribute__((ext_vector_type(4)));
typedef short s16x8 __attribute__((ext_vector_type(8)));
typedef unsigned int u32x4 __attribute__((ext_vector_type(4)));

__device__ __forceinline__ u16 f2bf(float f) {
    unsigned int u = __float_as_uint(f);
    unsigned int r = (u + 0x7fffu + ((u >> 16) & 1u)) >> 16;
    return (u16)r;
}
__device__ __forceinline__ float bf2f(u16 b) {
    return __uint_as_float(((unsigned int)b) << 16);
}
__device__ __forceinline__ float sigmf(float x) { return 1.0f / (1.0f + __expf(-x)); }

// ---- coherent primitives ----
__device__ __forceinline__ void stg_coh128(u16* p, u32x4 v) {
    asm volatile("global_store_dwordx4 %0, %1, off sc0 sc1" :: "v"(p), "v"(v) : "memory");
}
__device__ __forceinline__ u32 ldg_coh_u32(const u32* p) {
    u32 r;
    asm volatile("global_load_dword %0, %1, off sc0 sc1" : "=&v"(r) : "v"(p) : "memory");
    return r;
}
// plain 16B load as volatile asm (single VMEM instr; cannot be rematerialized)
__device__ __forceinline__ s16x8 ldg_pin(const u16* p) {
    s16x8 r;
    asm volatile("global_load_dwordx4 %0, %1, off" : "=&v"(r) : "v"(p) : "memory");
    return r;
}
__device__ __forceinline__ void waitvm0() {
    asm volatile("s_waitcnt vmcnt(0)" ::: "memory");
    __builtin_amdgcn_sched_barrier(0);
}

// ---- DMA global->LDS (16B/lane). dst wave-uniform; lane*16 implicit.
__device__ __forceinline__ void dmaA(const void* src, void* dst) {
    __builtin_amdgcn_global_load_lds((const __attribute__((address_space(1))) void*)src,
                                     (__attribute__((address_space(3))) void*)dst, 16, 0, 0);
}
__device__ __forceinline__ void dmaAcoh(const void* src, void* dst) {
    // SC0|SC1 = 17: IF-coherent read (bypass stale L2)
    __builtin_amdgcn_global_load_lds((const __attribute__((address_space(1))) void*)src,
                                     (__attribute__((address_space(3))) void*)dst, 16, 0, 17);
}

template <int I> struct IC { static constexpr int v = I; };
template <int N, int I = 0, typename F>
__device__ __forceinline__ void sfor(F&& f) {
    if constexpr (I < N) { f(IC<I>{}); sfor<N, I + 1, F>(static_cast<F&&>(f)); }
}

template <int N> __device__ __forceinline__ void waitvmN() {
    static_assert(N >= 0 && N <= 8, "unexpected vmcnt");
    if constexpr (N == 0)  asm volatile("s_waitcnt vmcnt(0)" ::: "memory");
    else if constexpr (N == 1)  asm volatile("s_waitcnt vmcnt(1)" ::: "memory");
    else if constexpr (N == 2)  asm volatile("s_waitcnt vmcnt(2)" ::: "memory");
    else if constexpr (N == 3)  asm volatile("s_waitcnt vmcnt(3)" ::: "memory");
    else if constexpr (N == 4)  asm volatile("s_waitcnt vmcnt(4)" ::: "memory");
    else if constexpr (N == 5)  asm volatile("s_waitcnt vmcnt(5)" ::: "memory");
    else if constexpr (N == 6)  asm volatile("s_waitcnt vmcnt(6)" ::: "memory");
    else if constexpr (N == 7)  asm volatile("s_waitcnt vmcnt(7)" ::: "memory");
    else if constexpr (N == 8)  asm volatile("s_waitcnt vmcnt(8)" ::: "memory");
    __builtin_amdgcn_sched_barrier(0);
}

// Pf bank-swizzled index: row-major [256][64] f32 with XOR on the m index.
__device__ __forceinline__ int PFI(int row, int m) {
    return row * 64 + (m ^ ((row & 7) << 2));
}

// ---------------- prep (unchanged) ----------------
__global__ void prep_kernel(const float* __restrict__ Wx0, const float* __restrict__ Wh0,
                            const float* __restrict__ bx0, const float* __restrict__ bh0,
                            const float* __restrict__ Wx1, const float* __restrict__ Wh1,
                            const float* __restrict__ bx1, const float* __restrict__ bh1,
                            const float* __restrict__ h0in, const float* __restrict__ x,
                            u16* __restrict__ Wpk0, u16* __restrict__ Wpk1,
                            u16* __restrict__ xpk, float* __restrict__ bcomb,
                            u16* __restrict__ h0buf, u16* __restrict__ h1buf,
                            u32* __restrict__ cnt) {
    const long long idx = (long long)blockIdx.x * 256 + threadIdx.x;
    const long long stride = (long long)gridDim.x * 256;
    if (idx < 8) cnt[idx * 16] = 0u;   // 8 counters, 64B apart

    for (long long i = idx; i < 128LL * 4 * 24 * 512; i += stride) {
        const int j = (int)(i & 7);
        const int lane = (int)((i >> 3) & 63);
        const int f = (int)(i >> 9);
        const int nt = f & 1;
        const int q = f >> 1;
        const int c = q % 12, r = q / 12;
        const int wv = r & 3, wg = r >> 2;
        const int pr = lane & 15, lh = lane >> 4;
        const int row = (nt * 2 + (pr >> 3)) * 1024 + wg * 8 + (pr & 7);
        const int k = (c * 4 + wv) * 32 + lh * 8 + j;
        const float v = (k < 512) ? Wx0[(size_t)row * 512 + k] : Wh0[(size_t)row * 1024 + (k - 512)];
        Wpk0[i] = f2bf(v);
    }
    for (long long i = idx; i < 128LL * 4 * 32 * 512; i += stride) {
        const int j = (int)(i & 7);
        const int lane = (int)((i >> 3) & 63);
        const int f = (int)(i >> 9);
        const int nt = f & 1;
        const int q = f >> 1;
        const int c = q & 15, r = q >> 4;
        const int wv = r & 3, wg = r >> 2;
        const int pr = lane & 15, lh = lane >> 4;
        const int row = (nt * 2 + (pr >> 3)) * 1024 + wg * 8 + (pr & 7);
        const int k = (c * 4 + wv) * 32 + lh * 8 + j;
        const float v = (k < 1024) ? Wx1[(size_t)row * 1024 + k] : Wh1[(size_t)row * 1024 + (k - 1024)];
        Wpk1[i] = f2bf(v);
    }
    // x -> bf16 [t][b][d]
    for (long long bi = idx; bi < 512LL * 64 * 64; bi += stride) {
        const int db = (int)(bi & 63);
        const int r = (int)((bi >> 6) & 63);
        const int t = (int)(bi >> 12);
        const float* sp = x + ((size_t)r * Sn + t) * Dn + db * 8;
        const float4 a = *(const float4*)sp;
        const float4 b = *(const float4*)(sp + 4);
        s16x8 v;
        v[0] = (short)f2bf(a.x); v[1] = (short)f2bf(a.y); v[2] = (short)f2bf(a.z); v[3] = (short)f2bf(a.w);
        v[4] = (short)f2bf(b.x); v[5] = (short)f2bf(b.y); v[6] = (short)f2bf(b.z); v[7] = (short)f2bf(b.w);
        *(s16x8*)&xpk[bi * 8] = v;
    }
    for (long long i = idx; i < 4096; i += stride) {
        bcomb[i] = bx0[i] + bh0[i];
        bcomb[4096 + i] = bx1[i] + bh1[i];
    }
    // initial h states: parity-1 slabs, PRE-SWIZZLED block layout
    for (long long bi = idx; bi < 8192; bi += stride) {
        const int ck = (int)(bi >> 10), w = (int)(bi & 1023);
        const int r = w >> 4, b = w & 15;
        const int cbl = b ^ (r & 7);
        const int k = ck * 128 + cbl * 8;
        s16x8 v0, v1;
#pragma unroll
        for (int j = 0; j < 8; ++j) {
            v0[j] = (short)f2bf(h0in[(size_t)r * Hn + k + j]);
            v1[j] = (short)f2bf(h0in[(size_t)BH + r * Hn + k + j]);
        }
        *(s16x8*)&h0buf[65536 + bi * 8] = v0;
        *(s16x8*)&h1buf[65536 + bi * 8] = v1;
    }
}

// ---------------- fence-free bounded grid barrier (128 arrivals/phase) ----------------
__device__ __forceinline__ void gbar(u32* cbase, int slot, u32 tgt, int& dead) {
    waitvm0();
    __syncthreads();
    if (threadIdx.x == 0 && !dead) {
        atomicAdd(cbase + slot * 16, 1u);
        int guard = 0;
        for (;;) {
            u32 t0 = ldg_coh_u32(cbase + 0 * 16), t1 = ldg_coh_u32(cbase + 1 * 16);
            u32 t2 = ldg_coh_u32(cbase + 2 * 16), t3 = ldg_coh_u32(cbase + 3 * 16);
            u32 t4 = ldg_coh_u32(cbase + 4 * 16), t5 = ldg_coh_u32(cbase + 5 * 16);
            u32 t6 = ldg_coh_u32(cbase + 6 * 16), t7 = ldg_coh_u32(cbase + 7 * 16);
            waitvm0();
            if (t0 + t1 + t2 + t3 + t4 + t5 + t6 + t7 >= tgt) break;
            __builtin_amdgcn_s_sleep(1);
            if (++guard > (1 << 12)) { dead = 1; break; }   // hardened: <2s worst-case total
        }
    }
    __syncthreads();
}

// ---------------- per-layer persistent loop ----------------
// NC chunks of 128 k (L0:12, L1:16); XC = chunks from first source (L0: xpk 4; L1: h0 8).
// 16 waves: wid = cg*8 + nt*4 + ks. Wave stages rows wid*4+lhi (1 DMA/chunk) and
// computes the nt-th B-fragment for its (cg,ks). Weights: NC frags resident in VGPRs.
template <int NC, int XC, int LAYER>
__device__ __forceinline__ void run_layer(const u16* __restrict__ xpk,
                                          const u16* __restrict__ Wpk,
                                          const float* __restrict__ bias,
                                          const float* __restrict__ c0in,
                                          u16* h0buf, u16* h1buf, u16* h1fin,
                                          u32* cnt, int wg, int slot, char* smem) {
    constexpr int LA = 7;                  // A lookahead (8-slot ring)
    const int tid = threadIdx.x;
    const int wid = tid >> 6, lane = tid & 63;
    const int ks = wid & 3, nt = (wid >> 2) & 1, cg = wid >> 3;
    const int ln15 = lane & 15, lhi = lane >> 4;
    const int vg = wg * 2 + cg;            // 8-col group index in [0,128)
    const int col0 = wg * 16;
    const int m_u = tid & 63, cp_u = (tid >> 6) & 7;  // cell update (tid<512 active)
    int dead = 0;
    float* Pf = (float*)smem;              // epilogue overlay (ring slots 0-3, 64 KB)
    u32* hstg = (u32*)(smem + 65536);      // epilogue overlay (slot 4 head, 2 KB)

    // ---- one-time: resident weights, NC frags (frag 2c+nt of stream vg*4+ks)
    const u16* wbase = Wpk + ((size_t)(vg * 4 + ks) * (2 * NC) + nt) * 512 + lane * 8;
    s16x8 wfr[NC];
    sfor<NC>([&](auto cc) { wfr[cc.v] = ldg_pin(wbase + (size_t)cc.v * 1024); });
    waitvm0();

    // staging geometry: wave stages rows wid*4 + lhi, k-block ln15 (1 KB/wave/chunk)
    const int srow = wid * 4 + lhi;
    const int xoff = srow * 1024 + ((ln15 ^ (srow & 7)) << 4);    // x: logical->swizzled
    const int wib = wid * 1024 + lane * 16;                        // h: pre-swizzled linear

    float bR[4][2];
#pragma unroll
    for (int g = 0; g < 4; ++g) {
        bR[g][0] = bias[g * 1024 + col0 + cp_u * 2 + 0];
        bR[g][1] = bias[g * 1024 + col0 + cp_u * 2 + 1];
    }
    float cr0 = c0in[(size_t)m_u * 1024 + col0 + cp_u * 2 + 0];
    float cr1 = c0in[(size_t)m_u * 1024 + col0 + cp_u * 2 + 1];

    for (int ph = 0; ph <= Sn; ++ph) {
        const bool active = (LAYER == 0) ? (ph < Sn) : (ph >= 1);
        if (active) {
            const int t = (LAYER == 0) ? ph : ph - 1;
            const char* hA = (const char*)h0buf + (size_t)((ph + 1) & 1) * SLAB;
            const char* hB = (const char*)h1buf + (size_t)(ph & 1) * SLAB;
            u16* hw = (LAYER == 0) ? (u16*)((char*)h0buf + (size_t)(ph & 1) * SLAB)
                                   : (u16*)((char*)h1buf + (size_t)((ph + 1) & 1) * SLAB);
            const char* xsl = (const char*)xpk + (size_t)t * 65536;

            auto issueA = [&](auto cc) {
                constexpr int c = cc.v;
                char* dst = smem + ((c & 7) << 14) + wid * 1024;   // wave-uniform
                if constexpr (LAYER == 0 && c < XC) {
                    dmaA(xsl + xoff + c * 256, dst);
                } else if constexpr (LAYER == 0) {
                    dmaAcoh(hA + ((c - XC) << 14) + wib, dst);
                } else if constexpr (c < XC) {
                    dmaAcoh(hA + (c << 14) + wib, dst);
                } else {
                    dmaAcoh(hB + ((c - XC) << 14) + wib, dst);
                }
            };

            // prologue: A chunks 0..LA-1 into slots 0..6
            sfor<LA>([&](auto k) { issueA(k); });

            f32x4 acc[4];
#pragma unroll
            for (int mi = 0; mi < 4; ++mi) acc[mi] = f32x4{0.f, 0.f, 0.f, 0.f};

            sfor<NC>([&](auto cc) {
                constexpr int c = cc.v;
                constexpr int W = (LA - 1 < NC - 1 - c) ? LA - 1 : NC - 1 - c;
                waitvmN<W>();                          // own chunk-c DMA done (A-only FIFO)
                __builtin_amdgcn_s_barrier();          // all waves' chunk-c staged;
                __builtin_amdgcn_sched_barrier(0);     //  slot (c-1)&7 free for overwrite
                if constexpr (c + LA < NC) issueA(IC<c + LA>{});
                const int ab = (c & 7) << 14;
#pragma unroll
                for (int mi = 0; mi < 4; ++mi) {
                    const int arow = mi * 16 + ln15;
                    const s16x8 af =
                        *(const s16x8*)&smem[ab + arow * 256 + (((ks * 4 + lhi) ^ (arow & 7)) << 4)];
                    acc[mi] = __builtin_amdgcn_mfma_f32_16x16x32_bf16(af, wfr[c], acc[mi], 0, 0, 0);
                }
            });

            // ---- epilogue: cross-wave reduction (Pf overlays ring slots 0-3 -> sync first)
            __syncthreads();
#pragma unroll
            for (int mi = 0; mi < 4; ++mi)
#pragma unroll
                for (int r = 0; r < 4; ++r) {
                    const int row = cg * 128 + ks * 32 + (nt * 2 + (ln15 >> 3)) * 8 + (ln15 & 7);
                    const int m = mi * 16 + lhi * 4 + r;
                    Pf[PFI(row, m)] = acc[mi][r];
                }
            __syncthreads();

            if (tid < 512) {   // fused cell update: thread owns (m_u, cols col0+2cp_u..+1)
                float sg[4][2];
#pragma unroll
                for (int g = 0; g < 4; ++g) { sg[g][0] = bR[g][0]; sg[g][1] = bR[g][1]; }
#pragma unroll
                for (int j = 0; j < 2; ++j) {
                    const int ci = cp_u * 2 + j;
                    const int cgj = ci >> 3, colw = ci & 7;
#pragma unroll
                    for (int k2 = 0; k2 < 4; ++k2)
#pragma unroll
                        for (int g = 0; g < 4; ++g)
                            sg[g][j] += Pf[PFI(cgj * 128 + k2 * 32 + g * 8 + colw, m_u)];
                }
                const float i0 = sigmf(sg[0][0]), f0 = sigmf(sg[1][0]), g0 = tanhf(sg[2][0]), o0 = sigmf(sg[3][0]);
                const float i1 = sigmf(sg[0][1]), f1 = sigmf(sg[1][1]), g1 = tanhf(sg[2][1]), o1 = sigmf(sg[3][1]);
                cr0 = f0 * cr0 + i0 * g0;
                cr1 = f1 * cr1 + i1 * g1;
                const u16 hb0 = f2bf(o0 * tanhf(cr0));
                const u16 hb1 = f2bf(o1 * tanhf(cr1));
                hstg[m_u * 8 + cp_u] = (u32)hb0 | ((u32)hb1 << 16);
            }
            __syncthreads();
            if (tid < 128) {   // one coherent 16B store per (row, 8-col half)
                const int r = tid >> 1, half = tid & 1;
                u32x4 hv;
                hv[0] = hstg[r * 8 + half * 4 + 0]; hv[1] = hstg[r * 8 + half * 4 + 1];
                hv[2] = hstg[r * 8 + half * 4 + 2]; hv[3] = hstg[r * 8 + half * 4 + 3];
                if (LAYER == 1 && ph == Sn) {
                    stg_coh128(&h1fin[(size_t)r * Hn + col0 + half * 8], hv);  // plain for FC
                } else {
                    const int cb = wg * 2 + half;          // block index in [0,128)
                    const int ck = cb >> 4, bl = cb & 15;
                    stg_coh128(hw + ck * 8192 + (r * 16 + (bl ^ (r & 7))) * 8, hv);
                }
            }
        }
        if (ph < Sn) gbar(cnt, slot, (u32)(ph + 1) * 128u, dead);
    }
    waitvm0();
}

__global__ __attribute__((amdgpu_flat_work_group_size(1024, 1024)))
void lstm_persist(const u16* __restrict__ xpk,
                  const u16* __restrict__ Wpk0,
                  const u16* __restrict__ Wpk1,
                  const float* __restrict__ bias,
                  const float* __restrict__ c0in,
                  u16* h0buf, u16* h1buf, u16* h1fin, u32* cnt) {
    __shared__ __align__(16) char smem[131072];   // 8-slot A ring; 1 WG/CU
    const int slot = blockIdx.x & 7;
    if (blockIdx.x < 64)
        run_layer<12, 4, 0>(xpk, Wpk0, bias, c0in, h0buf, h1buf, h1fin, cnt, blockIdx.x, slot, smem);
    else
        run_layer<16, 8, 1>(xpk, Wpk1, bias + 4096, c0in + BH, h0buf, h1buf, h1fin, cnt,
                            blockIdx.x - 64, slot, smem);
}

// ---------------- final FC + sigmoid ----------------
__global__ __launch_bounds__(256) void fc_out(const u16* __restrict__ h1,
                                              const float* __restrict__ fcW,
                                              const float* __restrict__ fcb,
                                              float* __restrict__ out) {
    const int b = blockIdx.x;  // 64
    __shared__ float hs[Hn];
    for (int k = threadIdx.x; k < Hn; k += 256) hs[k] = bf2f(h1[(size_t)b * Hn + k]);
    __syncthreads();
    const int o = threadIdx.x;  // 256
    float acc = fcb[o];
    const float4* wr = (const float4*)(fcW + (size_t)o * Hn);
    const float4* hv = (const float4*)hs;
#pragma unroll 8
    for (int k4 = 0; k4 < Hn / 4; ++k4) {
        const float4 w = wr[k4];
        const float4 h = hv[k4];
        acc += w.x * h.x + w.y * h.y + w.z * h.z + w.w * h.w;
    }
    out[(size_t)b * On + o] = sigmf(acc);
}

extern "C" void kernel_launch(void* const* d_in, const int* in_sizes, int n_in,
                              void* d_out, int out_size, void* d_ws, size_t ws_size,
                              hipStream_t stream) {
    (void)in_sizes; (void)n_in; (void)out_size; (void)ws_size;
    const float* x   = (const float*)d_in[0];
    const float* h0i = (const float*)d_in[1];
    const float* c0i = (const float*)d_in[2];
    const float* Wx0 = (const float*)d_in[3];
    const float* Wh0 = (const float*)d_in[4];
    const float* bx0 = (const float*)d_in[5];
    const float* bh0 = (const float*)d_in[6];
    const float* Wx1 = (const float*)d_in[7];
    const float* Wh1 = (const float*)d_in[8];
    const float* bx1 = (const float*)d_in[9];
    const float* bh1 = (const float*)d_in[10];
    const float* fcW = (const float*)d_in[11];
    const float* fcb = (const float*)d_in[12];
    float* out = (float*)d_out;

    char* ws = (char*)d_ws;
    u16* Wpk0   = (u16*)(ws + 0);            // 12,582,912 B
    u16* Wpk1   = (u16*)(ws + 12582912);     // 16,777,216 B
    u16* xpk    = (u16*)(ws + 29360128);     // 33,554,432 B  [t][b][d] bf16
    float* bias = (float*)(ws + 62914560);   // 32,768 B
    u16* h0buf  = (u16*)(ws + 62947328);     // 262,144 B (2 swizzled slabs)
    u16* h1buf  = (u16*)(ws + 63209472);     // 262,144 B
    u16* h1fin  = (u16*)(ws + 63471616);     // 131,072 B (plain, for FC)
    u32* cnt    = (u32*)(ws + 63602688);     // 512 B

    prep_kernel<<<2048, 256, 0, stream>>>(Wx0, Wh0, bx0, bh0, Wx1, Wh1, bx1, bh1,
                                          h0i, x, Wpk0, Wpk1, xpk, bias, h0buf, h1buf, cnt);

    lstm_persist<<<128, 1024, 0, stream>>>(xpk, Wpk0, Wpk1, bias, c0i, h0buf, h1buf, h1fin, cnt);

    fc_out<<<64, 256, 0, stream>>>(h1fin, fcW, fcb, out);
}

// Round 15
// 4916.757 us; speedup vs baseline: 1.1276x; 1.0398x over previous
//
#include <hip/hip_runtime.h>
#include <hip/hip_bf16.h>

// LSTM: B=64, S=512, D=512, H=1024, L=2, O=256
// Persistent kernel, DECOUPLED layer groups (no global barrier):
//   - L0 (WGs 0-63) and L1 (WGs 64-127) each have their own 64-arrival barrier.
//   - 4 rotating h0 slabs let L0 run up to 3 phases ahead; L1 (critical path)
//     finds its dependencies already satisfied -> pays only its own group barrier.
//   - L0 phase p: needs cnt0>=64p (own prev), cnt1>=64(p-3) (slab recycle).
//     L1 phase q (t=q): needs cnt0>=64(q+1) (h0[q] ready), cnt1>=64q (own prev).
//   - 16 waves/WG; weights VGPR-resident (NC frags/wave, loaded once).
//   - A-panel staged via global_load_lds into an 8-slot LDS ring, lookahead 7.
//   - h slabs PRE-SWIZZLED; h coherence via sc0 sc1 (IF); monotone counters.

namespace {
constexpr int Bn = 64, Sn = 512, Dn = 512, Hn = 1024, On = 256;
constexpr int BH = Bn * Hn;        // 65536
constexpr int SLAB = BH * 2;       // 131072 bytes per h slab (bf16)
}

typedef unsigned short u16;
typedef unsigned int u32;
typedef float f32x4 __attribute__((ext_vector_type(4)));
typedef short s16x8 __attribute__((ext_vector_type(8)));
typedef unsigned int u32x4 __attribute__((ext_vector_type(4)));

__device__ __forceinline__ u16 f2bf(float f) {
    unsigned int u = __float_as_uint(f);
    unsigned int r = (u + 0x7fffu + ((u >> 16) & 1u)) >> 16;
    return (u16)r;
}
__device__ __forceinline__ float bf2f(u16 b) {
    return __uint_as_float(((unsigned int)b) << 16);
}
__device__ __forceinline__ float sigmf(float x) { return 1.0f / (1.0f + __expf(-x)); }

// ---- coherent primitives ----
__device__ __forceinline__ void stg_coh128(u16* p, u32x4 v) {
    asm volatile("global_store_dwordx4 %0, %1, off sc0 sc1" :: "v"(p), "v"(v) : "memory");
}
__device__ __forceinline__ u32 ldg_coh_u32(const u32* p) {
    u32 r;
    asm volatile("global_load_dword %0, %1, off sc0 sc1" : "=&v"(r) : "v"(p) : "memory");
    return r;
}
// plain 16B load as volatile asm (single VMEM instr; cannot be rematerialized)
__device__ __forceinline__ s16x8 ldg_pin(const u16* p) {
    s16x8 r;
    asm volatile("global_load_dwordx4 %0, %1, off" : "=&v"(r) : "v"(p) : "memory");
    return r;
}
__device__ __forceinline__ void waitvm0() {
    asm volatile("s_waitcnt vmcnt(0)" ::: "memory");
    __builtin_amdgcn_sched_barrier(0);
}

// ---- DMA global->LDS (16B/lane). dst wave-uniform; lane*16 implicit.
__device__ __forceinline__ void dmaA(const void* src, void* dst) {
    __builtin_amdgcn_global_load_lds((const __attribute__((address_space(1))) void*)src,
                                     (__attribute__((address_space(3))) void*)dst, 16, 0, 0);
}
__device__ __forceinline__ void dmaAcoh(const void* src, void* dst) {
    // SC0|SC1 = 17: IF-coherent read (bypass stale L2)
    __builtin_amdgcn_global_load_lds((const __attribute__((address_space(1))) void*)src,
                                     (__attribute__((address_space(3))) void*)dst, 16, 0, 17);
}

template <int I> struct IC { static constexpr int v = I; };
template <int N, int I = 0, typename F>
__device__ __forceinline__ void sfor(F&& f) {
    if constexpr (I < N) { f(IC<I>{}); sfor<N, I + 1, F>(static_cast<F&&>(f)); }
}

template <int N> __device__ __forceinline__ void waitvmN() {
    static_assert(N >= 0 && N <= 8, "unexpected vmcnt");
    if constexpr (N == 0)  asm volatile("s_waitcnt vmcnt(0)" ::: "memory");
    else if constexpr (N == 1)  asm volatile("s_waitcnt vmcnt(1)" ::: "memory");
    else if constexpr (N == 2)  asm volatile("s_waitcnt vmcnt(2)" ::: "memory");
    else if constexpr (N == 3)  asm volatile("s_waitcnt vmcnt(3)" ::: "memory");
    else if constexpr (N == 4)  asm volatile("s_waitcnt vmcnt(4)" ::: "memory");
    else if constexpr (N == 5)  asm volatile("s_waitcnt vmcnt(5)" ::: "memory");
    else if constexpr (N == 6)  asm volatile("s_waitcnt vmcnt(6)" ::: "memory");
    else if constexpr (N == 7)  asm volatile("s_waitcnt vmcnt(7)" ::: "memory");
    else if constexpr (N == 8)  asm volatile("s_waitcnt vmcnt(8)" ::: "memory");
    __builtin_amdgcn_sched_barrier(0);
}

// Pf bank-swizzled index: row-major [256][64] f32 with XOR on the m index.
__device__ __forceinline__ int PFI(int row, int m) {
    return row * 64 + (m ^ ((row & 7) << 2));
}

// ---------------- prep ----------------
__global__ void prep_kernel(const float* __restrict__ Wx0, const float* __restrict__ Wh0,
                            const float* __restrict__ bx0, const float* __restrict__ bh0,
                            const float* __restrict__ Wx1, const float* __restrict__ Wh1,
                            const float* __restrict__ bx1, const float* __restrict__ bh1,
                            const float* __restrict__ h0in, const float* __restrict__ x,
                            u16* __restrict__ Wpk0, u16* __restrict__ Wpk1,
                            u16* __restrict__ xpk, float* __restrict__ bcomb,
                            u16* __restrict__ h0buf, u16* __restrict__ h1buf,
                            u32* __restrict__ cnt) {
    const long long idx = (long long)blockIdx.x * 256 + threadIdx.x;
    const long long stride = (long long)gridDim.x * 256;
    if (idx < 16) cnt[idx * 16] = 0u;   // cnt0: slots 0-7, cnt1: slots 8-15 (64B apart)

    for (long long i = idx; i < 128LL * 4 * 24 * 512; i += stride) {
        const int j = (int)(i & 7);
        const int lane = (int)((i >> 3) & 63);
        const int f = (int)(i >> 9);
        const int nt = f & 1;
        const int q = f >> 1;
        const int c = q % 12, r = q / 12;
        const int wv = r & 3, wg = r >> 2;
        const int pr = lane & 15, lh = lane >> 4;
        const int row = (nt * 2 + (pr >> 3)) * 1024 + wg * 8 + (pr & 7);
        const int k = (c * 4 + wv) * 32 + lh * 8 + j;
        const float v = (k < 512) ? Wx0[(size_t)row * 512 + k] : Wh0[(size_t)row * 1024 + (k - 512)];
        Wpk0[i] = f2bf(v);
    }
    for (long long i = idx; i < 128LL * 4 * 32 * 512; i += stride) {
        const int j = (int)(i & 7);
        const int lane = (int)((i >> 3) & 63);
        const int f = (int)(i >> 9);
        const int nt = f & 1;
        const int q = f >> 1;
        const int c = q & 15, r = q >> 4;
        const int wv = r & 3, wg = r >> 2;
        const int pr = lane & 15, lh = lane >> 4;
        const int row = (nt * 2 + (pr >> 3)) * 1024 + wg * 8 + (pr & 7);
        const int k = (c * 4 + wv) * 32 + lh * 8 + j;
        const float v = (k < 1024) ? Wx1[(size_t)row * 1024 + k] : Wh1[(size_t)row * 1024 + (k - 1024)];
        Wpk1[i] = f2bf(v);
    }
    // x -> bf16 [t][b][d]
    for (long long bi = idx; bi < 512LL * 64 * 64; bi += stride) {
        const int db = (int)(bi & 63);
        const int r = (int)((bi >> 6) & 63);
        const int t = (int)(bi >> 12);
        const float* sp = x + ((size_t)r * Sn + t) * Dn + db * 8;
        const float4 a = *(const float4*)sp;
        const float4 b = *(const float4*)(sp + 4);
        s16x8 v;
        v[0] = (short)f2bf(a.x); v[1] = (short)f2bf(a.y); v[2] = (short)f2bf(a.z); v[3] = (short)f2bf(a.w);
        v[4] = (short)f2bf(b.x); v[5] = (short)f2bf(b.y); v[6] = (short)f2bf(b.z); v[7] = (short)f2bf(b.w);
        *(s16x8*)&xpk[bi * 8] = v;
    }
    for (long long i = idx; i < 4096; i += stride) {
        bcomb[i] = bx0[i] + bh0[i];
        bcomb[4096 + i] = bx1[i] + bh1[i];
    }
    // initial h states (PRE-SWIZZLED): L0 phase 0 reads h0 slab (-1)&3 = 3;
    // L1 phase 0 reads h1 slab (-1)&1 = 1.
    for (long long bi = idx; bi < 8192; bi += stride) {
        const int ck = (int)(bi >> 10), w = (int)(bi & 1023);
        const int r = w >> 4, b = w & 15;
        const int cbl = b ^ (r & 7);
        const int k = ck * 128 + cbl * 8;
        s16x8 v0, v1;
#pragma unroll
        for (int j = 0; j < 8; ++j) {
            v0[j] = (short)f2bf(h0in[(size_t)r * Hn + k + j]);
            v1[j] = (short)f2bf(h0in[(size_t)BH + r * Hn + k + j]);
        }
        *(s16x8*)&h0buf[3 * 65536 + bi * 8] = v0;
        *(s16x8*)&h1buf[1 * 65536 + bi * 8] = v1;
    }
}

// ---------------- dual-counter wait (group-decoupled, bounded) ----------------
__device__ __forceinline__ void waitcnts(u32* cbase, u32 tgt0, u32 tgt1, int& dead) {
    __syncthreads();
    if (threadIdx.x == 0 && !dead) {
        int guard = 0;
        for (;;) {
            u32 a0 = ldg_coh_u32(cbase + 0 * 16),  a1 = ldg_coh_u32(cbase + 1 * 16);
            u32 a2 = ldg_coh_u32(cbase + 2 * 16),  a3 = ldg_coh_u32(cbase + 3 * 16);
            u32 a4 = ldg_coh_u32(cbase + 4 * 16),  a5 = ldg_coh_u32(cbase + 5 * 16);
            u32 a6 = ldg_coh_u32(cbase + 6 * 16),  a7 = ldg_coh_u32(cbase + 7 * 16);
            u32 b0 = ldg_coh_u32(cbase + 8 * 16),  b1 = ldg_coh_u32(cbase + 9 * 16);
            u32 b2 = ldg_coh_u32(cbase + 10 * 16), b3 = ldg_coh_u32(cbase + 11 * 16);
            u32 b4 = ldg_coh_u32(cbase + 12 * 16), b5 = ldg_coh_u32(cbase + 13 * 16);
            u32 b6 = ldg_coh_u32(cbase + 14 * 16), b7 = ldg_coh_u32(cbase + 15 * 16);
            waitvm0();
            const u32 s0 = a0 + a1 + a2 + a3 + a4 + a5 + a6 + a7;
            const u32 s1 = b0 + b1 + b2 + b3 + b4 + b5 + b6 + b7;
            if (s0 >= tgt0 && s1 >= tgt1) break;
            __builtin_amdgcn_s_sleep(1);
            if (++guard > (1 << 12)) { dead = 1; break; }
        }
    }
    __syncthreads();
}
// arrival: all stores acked -> one atomic into this group's split slot
__device__ __forceinline__ void arrive(u32* slotp, int& dead) {
    waitvm0();
    __syncthreads();
    if (threadIdx.x == 0 && !dead) atomicAdd(slotp, 1u);
}

// ---------------- per-layer persistent loop (decoupled groups) ----------------
// NC chunks of 128 k (L0:12, L1:16); XC = chunks from first source (L0: xpk 4; L1: h0 8).
// 16 waves: wid = cg*8 + nt*4 + ks. Weights: NC frags resident in VGPRs.
template <int NC, int XC, int LAYER>
__device__ __forceinline__ void run_layer(const u16* __restrict__ xpk,
                                          const u16* __restrict__ Wpk,
                                          const float* __restrict__ bias,
                                          const float* __restrict__ c0in,
                                          u16* h0buf, u16* h1buf, u16* h1fin,
                                          u32* cnt, int wg, char* smem) {
    constexpr int LA = 7;                  // A lookahead (8-slot ring)
    const int tid = threadIdx.x;
    const int wid = tid >> 6, lane = tid & 63;
    const int ks = wid & 3, nt = (wid >> 2) & 1, cg = wid >> 3;
    const int ln15 = lane & 15, lhi = lane >> 4;
    const int vg = wg * 2 + cg;            // 8-col group index in [0,128)
    const int col0 = wg * 16;
    const int m_u = tid & 63, cp_u = (tid >> 6) & 7;  // cell update (tid<512 active)
    int dead = 0;
    float* Pf = (float*)smem;              // epilogue overlay (ring slots 0-3, 64 KB)
    u32* hstg = (u32*)(smem + 65536);      // epilogue overlay (slot 4 head, 2 KB)
    u32* slotp = cnt + (LAYER == 0 ? 0 : 128) + (wg & 7) * 16;

    // ---- one-time: resident weights, NC frags (frag 2c+nt of stream vg*4+ks)
    const u16* wbase = Wpk + ((size_t)(vg * 4 + ks) * (2 * NC) + nt) * 512 + lane * 8;
    s16x8 wfr[NC];
    sfor<NC>([&](auto cc) { wfr[cc.v] = ldg_pin(wbase + (size_t)cc.v * 1024); });
    waitvm0();

    // staging geometry: wave stages rows wid*4 + lhi, k-block ln15 (1 KB/wave/chunk)
    const int srow = wid * 4 + lhi;
    const int xoff = srow * 1024 + ((ln15 ^ (srow & 7)) << 4);    // x: logical->swizzled
    const int wib = wid * 1024 + lane * 16;                        // h: pre-swizzled linear

    float bR[4][2];
#pragma unroll
    for (int g = 0; g < 4; ++g) {
        bR[g][0] = bias[g * 1024 + col0 + cp_u * 2 + 0];
        bR[g][1] = bias[g * 1024 + col0 + cp_u * 2 + 1];
    }
    float cr0 = c0in[(size_t)m_u * 1024 + col0 + cp_u * 2 + 0];
    float cr1 = c0in[(size_t)m_u * 1024 + col0 + cp_u * 2 + 1];

    for (int p = 0; p < Sn; ++p) {
        // ---- dependency wait (decoupled)
        if constexpr (LAYER == 0) {
            const u32 tgt0 = (p >= 1) ? 64u * (u32)p : 0u;          // own prev phase done
            const u32 tgt1 = (p >= 4) ? 64u * (u32)(p - 3) : 0u;    // L1 freed slab p&3
            waitcnts(cnt, tgt0, tgt1, dead);
        } else {
            const u32 tgt0 = 64u * (u32)(p + 1);                    // h0[p] complete
            const u32 tgt1 = (p >= 1) ? 64u * (u32)p : 0u;          // own prev phase done
            waitcnts(cnt, tgt0, tgt1, dead);
        }

        const char* hA;
        const char* hB = nullptr;
        u16* hw;
        const char* xsl = nullptr;
        if constexpr (LAYER == 0) {
            hA = (const char*)h0buf + (size_t)((p - 1) & 3) * SLAB;   // h0[p-1]
            hw = (u16*)((char*)h0buf + (size_t)(p & 3) * SLAB);       // h0[p]
            xsl = (const char*)xpk + (size_t)p * 65536;
        } else {
            hA = (const char*)h0buf + (size_t)(p & 3) * SLAB;         // h0[p]
            hB = (const char*)h1buf + (size_t)((p - 1) & 1) * SLAB;   // h1[p-1]
            hw = (u16*)((char*)h1buf + (size_t)(p & 1) * SLAB);       // h1[p]
        }

        auto issueA = [&](auto cc) {
            constexpr int c = cc.v;
            char* dst = smem + ((c & 7) << 14) + wid * 1024;   // wave-uniform
            if constexpr (LAYER == 0 && c < XC) {
                dmaA(xsl + xoff + c * 256, dst);
            } else if constexpr (LAYER == 0) {
                dmaAcoh(hA + ((c - XC) << 14) + wib, dst);
            } else if constexpr (c < XC) {
                dmaAcoh(hA + (c << 14) + wib, dst);
            } else {
                dmaAcoh(hB + ((c - XC) << 14) + wib, dst);
            }
        };

        // prologue: A chunks 0..LA-1 into slots 0..6
        sfor<LA>([&](auto k) { issueA(k); });

        f32x4 acc[4];
#pragma unroll
        for (int mi = 0; mi < 4; ++mi) acc[mi] = f32x4{0.f, 0.f, 0.f, 0.f};

        sfor<NC>([&](auto cc) {
            constexpr int c = cc.v;
            constexpr int W = (LA - 1 < NC - 1 - c) ? LA - 1 : NC - 1 - c;
            waitvmN<W>();                          // own chunk-c DMA done (A-only FIFO)
            __builtin_amdgcn_s_barrier();          // all waves' chunk-c staged;
            __builtin_amdgcn_sched_barrier(0);     //  slot (c-1)&7 free for overwrite
            if constexpr (c + LA < NC) issueA(IC<c + LA>{});
            const int ab = (c & 7) << 14;
#pragma unroll
            for (int mi = 0; mi < 4; ++mi) {
                const int arow = mi * 16 + ln15;
                const s16x8 af =
                    *(const s16x8*)&smem[ab + arow * 256 + (((ks * 4 + lhi) ^ (arow & 7)) << 4)];
                acc[mi] = __builtin_amdgcn_mfma_f32_16x16x32_bf16(af, wfr[c], acc[mi], 0, 0, 0);
            }
        });

        // ---- epilogue: cross-wave reduction (Pf overlays ring slots 0-3 -> sync first)
        __syncthreads();
#pragma unroll
        for (int mi = 0; mi < 4; ++mi)
#pragma unroll
            for (int r = 0; r < 4; ++r) {
                const int row = cg * 128 + ks * 32 + (nt * 2 + (ln15 >> 3)) * 8 + (ln15 & 7);
                const int m = mi * 16 + lhi * 4 + r;
                Pf[PFI(row, m)] = acc[mi][r];
            }
        __syncthreads();

        if (tid < 512) {   // fused cell update: thread owns (m_u, cols col0+2cp_u..+1)
            float sg[4][2];
#pragma unroll
            for (int g = 0; g < 4; ++g) { sg[g][0] = bR[g][0]; sg[g][1] = bR[g][1]; }
#pragma unroll
            for (int j = 0; j < 2; ++j) {
                const int ci = cp_u * 2 + j;
                const int cgj = ci >> 3, colw = ci & 7;
#pragma unroll
                for (int k2 = 0; k2 < 4; ++k2)
#pragma unroll
                    for (int g = 0; g < 4; ++g)
                        sg[g][j] += Pf[PFI(cgj * 128 + k2 * 32 + g * 8 + colw, m_u)];
            }
            const float i0 = sigmf(sg[0][0]), f0 = sigmf(sg[1][0]), g0 = tanhf(sg[2][0]), o0 = sigmf(sg[3][0]);
            const float i1 = sigmf(sg[0][1]), f1 = sigmf(sg[1][1]), g1 = tanhf(sg[2][1]), o1 = sigmf(sg[3][1]);
            cr0 = f0 * cr0 + i0 * g0;
            cr1 = f1 * cr1 + i1 * g1;
            const u16 hb0 = f2bf(o0 * tanhf(cr0));
            const u16 hb1 = f2bf(o1 * tanhf(cr1));
            hstg[m_u * 8 + cp_u] = (u32)hb0 | ((u32)hb1 << 16);
        }
        __syncthreads();
        if (tid < 128) {   // one coherent 16B store per (row, 8-col half)
            const int r = tid >> 1, half = tid & 1;
            u32x4 hv;
            hv[0] = hstg[r * 8 + half * 4 + 0]; hv[1] = hstg[r * 8 + half * 4 + 1];
            hv[2] = hstg[r * 8 + half * 4 + 2]; hv[3] = hstg[r * 8 + half * 4 + 3];
            if (LAYER == 1 && p == Sn - 1) {
                stg_coh128(&h1fin[(size_t)r * Hn + col0 + half * 8], hv);  // plain for FC
            } else {
                const int cb = wg * 2 + half;          // block index in [0,128)
                const int ck = cb >> 4, bl = cb & 15;
                stg_coh128(hw + ck * 8192 + (r * 16 + (bl ^ (r & 7))) * 8, hv);
            }
        }
        arrive(slotp, dead);   // stores acked -> signal this group's counter
    }
    waitvm0();
}

__global__ __attribute__((amdgpu_flat_work_group_size(1024, 1024)))
__attribute__((amdgpu_waves_per_eu(4, 4)))
void lstm_persist(const u16* __restrict__ xpk,
                  const u16* __restrict__ Wpk0,
                  const u16* __restrict__ Wpk1,
                  const float* __restrict__ bias,
                  const float* __restrict__ c0in,
                  u16* h0buf, u16* h1buf, u16* h1fin, u32* cnt) {
    __shared__ __align__(16) char smem[131072];   // 8-slot A ring; 1 WG/CU
    if (blockIdx.x < 64)
        run_layer<12, 4, 0>(xpk, Wpk0, bias, c0in, h0buf, h1buf, h1fin, cnt, blockIdx.x, smem);
    else
        run_layer<16, 8, 1>(xpk, Wpk1, bias + 4096, c0in + BH, h0buf, h1buf, h1fin, cnt,
                            blockIdx.x - 64, smem);
}

// ---------------- final FC + sigmoid ----------------
__global__ __launch_bounds__(256) void fc_out(const u16* __restrict__ h1,
                                              const float* __restrict__ fcW,
                                              const float* __restrict__ fcb,
                                              float* __restrict__ out) {
    const int b = blockIdx.x;  // 64
    __shared__ float hs[Hn];
    for (int k = threadIdx.x; k < Hn; k += 256) hs[k] = bf2f(h1[(size_t)b * Hn + k]);
    __syncthreads();
    const int o = threadIdx.x;  // 256
    float acc = fcb[o];
    const float4* wr = (const float4*)(fcW + (size_t)o * Hn);
    const float4* hv = (const float4*)hs;
#pragma unroll 8
    for (int k4 = 0; k4 < Hn / 4; ++k4) {
        const float4 w = wr[k4];
        const float4 h = hv[k4];
        acc += w.x * h.x + w.y * h.y + w.z * h.z + w.w * h.w;
    }
    out[(size_t)b * On + o] = sigmf(acc);
}

extern "C" void kernel_launch(void* const* d_in, const int* in_sizes, int n_in,
                              void* d_out, int out_size, void* d_ws, size_t ws_size,
                              hipStream_t stream) {
    (void)in_sizes; (void)n_in; (void)out_size; (void)ws_size;
    const float* x   = (const float*)d_in[0];
    const float* h0i = (const float*)d_in[1];
    const float* c0i = (const float*)d_in[2];
    const float* Wx0 = (const float*)d_in[3];
    const float* Wh0 = (const float*)d_in[4];
    const float* bx0 = (const float*)d_in[5];
    const float* bh0 = (const float*)d_in[6];
    const float* Wx1 = (const float*)d_in[7];
    const float* Wh1 = (const float*)d_in[8];
    const float* bx1 = (const float*)d_in[9];
    const float* bh1 = (const float*)d_in[10];
    const float* fcW = (const float*)d_in[11];
    const float* fcb = (const float*)d_in[12];
    float* out = (float*)d_out;

    char* ws = (char*)d_ws;
    u16* Wpk0   = (u16*)(ws + 0);            // 12,582,912 B
    u16* Wpk1   = (u16*)(ws + 12582912);     // 16,777,216 B
    u16* xpk    = (u16*)(ws + 29360128);     // 33,554,432 B  [t][b][d] bf16
    float* bias = (float*)(ws + 62914560);   // 32,768 B
    u16* h0buf  = (u16*)(ws + 62947328);     // 524,288 B (4 swizzled slabs)
    u16* h1buf  = (u16*)(ws + 63471616);     // 262,144 B (2 swizzled slabs)
    u16* h1fin  = (u16*)(ws + 63733760);     // 131,072 B (plain, for FC)
    u32* cnt    = (u32*)(ws + 63864832);     // 1,024 B (16 split counters)

    prep_kernel<<<2048, 256, 0, stream>>>(Wx0, Wh0, bx0, bh0, Wx1, Wh1, bx1, bh1,
                                          h0i, x, Wpk0, Wpk1, xpk, bias, h0buf, h1buf, cnt);

    lstm_persist<<<128, 1024, 0, stream>>>(xpk, Wpk0, Wpk1, bias, c0i, h0buf, h1buf, h1fin, cnt);

    fc_out<<<64, 256, 0, stream>>>(h1fin, fcW, fcb, out);
}